// Round 4
// baseline (212.181 us; speedup 1.0000x reference)
//
#include <hip/hip_runtime.h>

#define N_NODES 100000
#define N_EDGES 1000000
#define N_REL 3
#define N_GRAPHS 512
#define VOCAB 10000
#define DIM 64

#define SCAN_B 1024
#define N_SCAN_BLOCKS ((N_NODES + SCAN_B - 1) / SCAN_B)   // 98

// ---------------------------------------------------------------------------
// Kernel 1: build transformed tables T[m][v][j], m=0 root, m=1..3 relations.
// T[m] = embed_table @ W_m. 4 rows per wave; float4 everywhere.
__global__ void build_tables(const float* __restrict__ embed,
                             const float* __restrict__ W_rel,
                             const float* __restrict__ W_root,
                             float* __restrict__ T) {
    int tid  = blockIdx.x * 256 + threadIdx.x;
    int l    = tid & 63;
    int wave = tid >> 6;              // 0..9999
    int sub  = l >> 4;                // row-within-wave 0..3
    int q    = l & 15;                // feature quad
    int row  = wave * 4 + sub;        // wave never crosses m (10000%4==0)
    int m    = row / VOCAB;
    int v    = row - m * VOCAB;
    const float* W = (m == 0) ? W_root : (W_rel + (size_t)(m - 1) * DIM * DIM);
    float4 e4  = *(const float4*)(embed + (size_t)v * DIM + q * 4);
    float4 acc = {0.f, 0.f, 0.f, 0.f};
#pragma unroll
    for (int kk = 0; kk < 16; ++kk) {
        int srcl = sub * 16 + kk;
        float ex = __shfl(e4.x, srcl, 64);
        float ey = __shfl(e4.y, srcl, 64);
        float ez = __shfl(e4.z, srcl, 64);
        float ew = __shfl(e4.w, srcl, 64);
        const float4 w0 = *(const float4*)(W + (4 * kk + 0) * DIM + q * 4);
        const float4 w1 = *(const float4*)(W + (4 * kk + 1) * DIM + q * 4);
        const float4 w2 = *(const float4*)(W + (4 * kk + 2) * DIM + q * 4);
        const float4 w3 = *(const float4*)(W + (4 * kk + 3) * DIM + q * 4);
        acc.x += ex * w0.x; acc.y += ex * w0.y; acc.z += ex * w0.z; acc.w += ex * w0.w;
        acc.x += ey * w1.x; acc.y += ey * w1.y; acc.z += ey * w1.z; acc.w += ey * w1.w;
        acc.x += ez * w2.x; acc.y += ez * w2.y; acc.z += ez * w2.z; acc.w += ez * w2.w;
        acc.x += ew * w3.x; acc.y += ew * w3.y; acc.z += ew * w3.z; acc.w += ew * w3.w;
    }
    *(float4*)(T + (size_t)row * DIM + q * 4) = acc;
}

// ---------------------------------------------------------------------------
// Kernel 2: fused degree histogram + packed payload build (edge order).
__global__ void edge_prep(const int* __restrict__ src,
                          const int* __restrict__ dst,
                          const int* __restrict__ etype,
                          const int* __restrict__ x,
                          int* __restrict__ deg,
                          unsigned short* __restrict__ payload) {
    int e = blockIdx.x * 256 + threadIdx.x;
    if (e >= N_EDGES) return;
    atomicAdd(&deg[dst[e]], 1);
    payload[e] = (unsigned short)(((unsigned)x[src[e]] << 2) | (unsigned)etype[e]);
}

// ---------------------------------------------------------------------------
// Kernel 3a: per-block exclusive scan of deg (1024-wide blocks).
__global__ __launch_bounds__(SCAN_B)
void scan_block(const int* __restrict__ deg, int* __restrict__ off,
                int* __restrict__ bsum) {
    __shared__ int s[SCAN_B];
    int i = blockIdx.x * SCAN_B + threadIdx.x;
    int v = (i < N_NODES) ? deg[i] : 0;
    s[threadIdx.x] = v;
    __syncthreads();
    for (int d = 1; d < SCAN_B; d <<= 1) {
        int t = (threadIdx.x >= d) ? s[threadIdx.x - d] : 0;
        __syncthreads();
        s[threadIdx.x] += t;
        __syncthreads();
    }
    if (i < N_NODES) off[i] = s[threadIdx.x] - v;     // exclusive
    if (threadIdx.x == SCAN_B - 1) bsum[blockIdx.x] = s[SCAN_B - 1];
}

// Kernel 3b: wave-parallel exclusive scan of the 98 block sums (1 wave).
__global__ void scan_bsum(int* __restrict__ bsum) {
    int l = threadIdx.x;               // 0..63
    int v0 = (l < N_SCAN_BLOCKS) ? bsum[l] : 0;
    int s = v0;
#pragma unroll
    for (int d = 1; d < 64; d <<= 1) {
        int t = __shfl_up(s, d, 64);
        if (l >= d) s += t;
    }
    int tot0 = __shfl(s, 63, 64);
    if (l < N_SCAN_BLOCKS) bsum[l] = s - v0;           // exclusive
    int i2 = 64 + l;
    int v1 = (i2 < N_SCAN_BLOCKS) ? bsum[i2] : 0;      // disjoint from writes above
    int s2 = v1;
#pragma unroll
    for (int d = 1; d < 64; d <<= 1) {
        int t = __shfl_up(s2, d, 64);
        if (l >= d) s2 += t;
    }
    if (i2 < N_SCAN_BLOCKS) bsum[i2] = tot0 + s2 - v1;
}

// Kernel 3c: add block offsets; also init cursor and off[N].
__global__ void scan_add(int* __restrict__ off, const int* __restrict__ bsum,
                         int* __restrict__ cursor) {
    int i = blockIdx.x * 256 + threadIdx.x;
    if (i < N_NODES) {
        int o = off[i] + bsum[i >> 10];
        off[i] = o;
        cursor[i] = o;
    }
    if (i == 0) off[N_NODES] = N_EDGES;
}

// ---------------------------------------------------------------------------
// Kernel 4: CSR position scatter (coalesced payload read, 2B scattered store).
__global__ void scatter_pos(const int* __restrict__ dst,
                            const unsigned short* __restrict__ payload,
                            int* __restrict__ cursor,
                            unsigned short* __restrict__ elist) {
    int e = blockIdx.x * 256 + threadIdx.x;
    if (e >= N_EDGES) return;
    int pos = atomicAdd(&cursor[dst[e]], 1);
    elist[pos] = payload[e];
}

// ---------------------------------------------------------------------------
// Kernel 5 v3: per-dst aggregation, whole 64-edge chunk in flight.
// lane = (g<<4)|q : g = edge-slot group (4), q = feature quad (16).
// Counts via ballot; accumulation via fully unrolled predication-free
// k-segments (invalid slots -> dummy row scaled by 0), wave-uniform break.
__global__ void aggregate(const int* __restrict__ x,
                          const int* __restrict__ off,
                          const unsigned short* __restrict__ elist,
                          const float* __restrict__ T,
                          const float* __restrict__ bias,
                          float* __restrict__ node_out) {
    int tid = blockIdx.x * 256 + threadIdx.x;
    int w = tid >> 6;                  // dst node id
    if (w >= N_NODES) return;
    int l = tid & 63;
    int g = l >> 4;                    // edge-slot group
    int q = l & 15;                    // feature quad
    int beg = off[w], end = off[w + 1];

    // per-relation counts: one ballot per relation per 64-edge chunk
    int c0 = 0, c1 = 0, c2 = 0;
    for (int cb = beg; cb < end; cb += 64) {
        int idx = cb + l;
        unsigned pl = (idx < end) ? (unsigned)elist[idx] : 0xFFFFu;  // r=3 sentinel
        int r = (int)(pl & 3u);
        c0 += __popcll(__ballot(r == 0));
        c1 += __popcll(__ballot(r == 1));
        c2 += __popcll(__ballot(r == 2));
    }
    float inv0 = 1.f / fmaxf((float)c0, 1.f);
    float inv1 = 1.f / fmaxf((float)c1, 1.f);
    float inv2 = 1.f / fmaxf((float)c2, 1.f);

    float4 acc = {0.f, 0.f, 0.f, 0.f};
    for (int cb = beg; cb < end; cb += 64) {
        int idx = cb + l;
        unsigned pl = (idx < end) ? (unsigned)elist[idx] : 0xFFFFu;  // L1-hot reload
        int rem = end - cb; if (rem > 64) rem = 64;
#pragma unroll
        for (int k = 0; k < 16; ++k) {
            if (k * 4 >= rem) break;                     // wave-uniform exit
            unsigned p = __shfl(pl, k * 4 + g, 64);      // slot k*4+g payload
            bool valid = (p != 0xFFFFu);
            int r = valid ? (int)(p & 3u) : 0;
            int v = valid ? (int)(p >> 2) : 0;
            float iv = (r == 0) ? inv0 : ((r == 1) ? inv1 : inv2);
            iv = valid ? iv : 0.f;
            const float4 t = *(const float4*)(T + ((size_t)(1 + r) * VOCAB + v) * DIM + q * 4);
            acc.x += t.x * iv; acc.y += t.y * iv;
            acc.z += t.z * iv; acc.w += t.w * iv;
        }
    }
    // combine the 4 edge-slot groups
    acc.x += __shfl_xor(acc.x, 16, 64); acc.x += __shfl_xor(acc.x, 32, 64);
    acc.y += __shfl_xor(acc.y, 16, 64); acc.y += __shfl_xor(acc.y, 32, 64);
    acc.z += __shfl_xor(acc.z, 16, 64); acc.z += __shfl_xor(acc.z, 32, 64);
    acc.w += __shfl_xor(acc.w, 16, 64); acc.w += __shfl_xor(acc.w, 32, 64);

    if (g == 0) {                      // lanes 0..15 write the 64-float row
        int v0 = x[w];
        const float4 rt = *(const float4*)(T + (size_t)v0 * DIM + q * 4);
        const float4 b4 = *(const float4*)(bias + q * 4);
        float4 o;
        o.x = fmaxf(rt.x + b4.x + acc.x, 0.f);
        o.y = fmaxf(rt.y + b4.y + acc.y, 0.f);
        o.z = fmaxf(rt.z + b4.z + acc.z, 0.f);
        o.w = fmaxf(rt.w + b4.w + acc.w, 0.f);
        *(float4*)(node_out + (size_t)w * DIM + q * 4) = o;
    }
}

// ---------------------------------------------------------------------------
// Kernel 6: per-graph mean pool + 64->2 linear. batch is SORTED.
__device__ __forceinline__ int lbound(const int* __restrict__ b, int val) {
    int lo = 0, hi = N_NODES;
    while (lo < hi) {
        int mid = (lo + hi) >> 1;
        if (b[mid] < val) lo = mid + 1; else hi = mid;
    }
    return lo;
}

__global__ void pool_linear(const int* __restrict__ batch,
                            const float* __restrict__ node_out,
                            const float* __restrict__ lin_W,
                            const float* __restrict__ lin_b,
                            float* __restrict__ out) {
    __shared__ float sh[256];
    int g = blockIdx.x;
    int lane = threadIdx.x & 63;
    int w = threadIdx.x >> 6;      // 0..3
    int s = lbound(batch, g);
    int e = lbound(batch, g + 1);
    float acc = 0.f;
    for (int i = s + w; i < e; i += 4)
        acc += node_out[(size_t)i * DIM + lane];
    sh[threadIdx.x] = acc;
    __syncthreads();
    if (w == 0) {
        float tot = sh[lane] + sh[64 + lane] + sh[128 + lane] + sh[192 + lane];
        float cnt = (float)(e - s);
        float mean = (e > s) ? tot / cnt : 0.f;
        float p0 = mean * lin_W[lane * 2 + 0];
        float p1 = mean * lin_W[lane * 2 + 1];
#pragma unroll
        for (int off2 = 32; off2 > 0; off2 >>= 1) {
            p0 += __shfl_down(p0, off2, 64);
            p1 += __shfl_down(p1, off2, 64);
        }
        if (lane == 0) {
            out[g * 2 + 0] = p0 + lin_b[0];
            out[g * 2 + 1] = p1 + lin_b[1];
        }
    }
}

// ---------------------------------------------------------------------------
extern "C" void kernel_launch(void* const* d_in, const int* in_sizes, int n_in,
                              void* d_out, int out_size, void* d_ws, size_t ws_size,
                              hipStream_t stream) {
    const int*   x      = (const int*)d_in[0];
    const int*   eidx   = (const int*)d_in[1];   // [2, E]
    const int*   etype  = (const int*)d_in[2];
    const int*   batch  = (const int*)d_in[3];
    const float* embed  = (const float*)d_in[4];
    const float* W_rel  = (const float*)d_in[5];
    const float* W_root = (const float*)d_in[6];
    const float* bias   = (const float*)d_in[7];
    const float* lin_W  = (const float*)d_in[8];
    const float* lin_b  = (const float*)d_in[9];
    float* out = (float*)d_out;

    const int* src = eidx;
    const int* dst = eidx + N_EDGES;

    // Workspace layout (bytes):
    //   elist    : 1M * 2        = 2,000,000  (first 400,000 aliased as deg:
    //                                          deg dead before elist written)
    //   off      : (N+1)*4       =   400,016 (padded)
    //   cursor   : N*4           =   400,000
    //   bsum     : 98*4          =     2,160 (padded to keep T at +2,802,176)
    //   T        : 4*VOCAB*64*4  = 10,240,000
    //   node_out : N*64*4        = 25,600,000  (first 2,000,000 aliased as
    //                              payload: payload dead before aggregate)
    char* ws = (char*)d_ws;
    unsigned short* elist = (unsigned short*)(ws);
    int* deg    = (int*)(ws);                    // alias: dead before elist written
    int* off    = (int*)(ws + 2000000);
    int* cursor = (int*)(ws + 2400016);
    int* bsum   = (int*)(ws + 2800016);
    float* T        = (float*)(ws + 2802176);
    float* node_out = (float*)(ws + 13042176);
    unsigned short* payload = (unsigned short*)(ws + 13042176);  // alias: dead before node_out written

    // Zero only the degree histogram.
    hipMemsetAsync(deg, 0, N_NODES * sizeof(int), stream);

    // 1. fused histogram + payload build
    edge_prep<<<(N_EDGES + 255) / 256, 256, 0, stream>>>(src, dst, etype, x, deg, payload);

    // 2. exclusive scan deg -> off (+cursor copy)
    scan_block<<<N_SCAN_BLOCKS, SCAN_B, 0, stream>>>(deg, off, bsum);
    scan_bsum<<<1, 64, 0, stream>>>(bsum);
    scan_add<<<(N_NODES + 255) / 256, 256, 0, stream>>>(off, bsum, cursor);

    // 3. CSR scatter (overwrites deg alias region — deg is dead)
    scatter_pos<<<(N_EDGES + 255) / 256, 256, 0, stream>>>(dst, payload, cursor, elist);

    // 4. transformed tables (needed only by aggregate)
    build_tables<<<(4 * VOCAB) / 16, 256, 0, stream>>>(embed, W_rel, W_root, T);

    // 5. per-node aggregation (no atomics, full chunk of loads in flight)
    aggregate<<<(N_NODES * 64) / 256, 256, 0, stream>>>(x, off, elist, T, bias, node_out);

    // 6. per-graph pool + linear (no atomics)
    pool_linear<<<N_GRAPHS, 256, 0, stream>>>(batch, node_out, lin_W, lin_b, out);
}

// Round 5
// 154.304 us; speedup vs baseline: 1.3751x; 1.3751x over previous
//
#include <hip/hip_runtime.h>

#define N_NODES 100000
#define N_EDGES 1000000
#define N_GRAPHS 512
#define VOCAB 10000
#define DIM 64

#define SCAN_B 1024
#define N_SCAN_BLOCKS ((N_NODES + SCAN_B - 1) / SCAN_B)   // 98

// ---------------------------------------------------------------------------
// Kernel 1: build transformed tables T[m][v][j], m=0 root, m=1..3 relations.
// T[m] = embed_table @ W_m. 4 rows per wave; float4 everywhere.
__global__ void build_tables(const float* __restrict__ embed,
                             const float* __restrict__ W_rel,
                             const float* __restrict__ W_root,
                             float* __restrict__ T) {
    int tid  = blockIdx.x * 256 + threadIdx.x;
    int l    = tid & 63;
    int wave = tid >> 6;              // 0..9999
    int sub  = l >> 4;                // row-within-wave 0..3
    int q    = l & 15;                // feature quad
    int row  = wave * 4 + sub;        // wave never crosses m (10000%4==0)
    int m    = row / VOCAB;
    int v    = row - m * VOCAB;
    const float* W = (m == 0) ? W_root : (W_rel + (size_t)(m - 1) * DIM * DIM);
    float4 e4  = *(const float4*)(embed + (size_t)v * DIM + q * 4);
    float4 acc = {0.f, 0.f, 0.f, 0.f};
#pragma unroll
    for (int kk = 0; kk < 16; ++kk) {
        int srcl = sub * 16 + kk;
        float ex = __shfl(e4.x, srcl, 64);
        float ey = __shfl(e4.y, srcl, 64);
        float ez = __shfl(e4.z, srcl, 64);
        float ew = __shfl(e4.w, srcl, 64);
        const float4 w0 = *(const float4*)(W + (4 * kk + 0) * DIM + q * 4);
        const float4 w1 = *(const float4*)(W + (4 * kk + 1) * DIM + q * 4);
        const float4 w2 = *(const float4*)(W + (4 * kk + 2) * DIM + q * 4);
        const float4 w3 = *(const float4*)(W + (4 * kk + 3) * DIM + q * 4);
        acc.x += ex * w0.x; acc.y += ex * w0.y; acc.z += ex * w0.z; acc.w += ex * w0.w;
        acc.x += ey * w1.x; acc.y += ey * w1.y; acc.z += ey * w1.z; acc.w += ey * w1.w;
        acc.x += ez * w2.x; acc.y += ez * w2.y; acc.z += ez * w2.z; acc.w += ez * w2.w;
        acc.x += ew * w3.x; acc.y += ew * w3.y; acc.z += ew * w3.z; acc.w += ew * w3.w;
    }
    *(float4*)(T + (size_t)row * DIM + q * 4) = acc;
}

// ---------------------------------------------------------------------------
// Kernel 2: fused histogram + rank + payload. The histogram atomic RETURNS
// this edge's within-dst rank; pack (payload<<16)|rank in one u32.
__global__ void edge_prep(const int* __restrict__ src,
                          const int* __restrict__ dst,
                          const int* __restrict__ etype,
                          const int* __restrict__ x,
                          int* __restrict__ deg,
                          unsigned* __restrict__ combo) {
    int e = blockIdx.x * 256 + threadIdx.x;
    if (e >= N_EDGES) return;
    int rank = atomicAdd(&deg[dst[e]], 1);             // rank < 2^16 (deg ~ Poisson(10))
    unsigned payload = ((unsigned)x[src[e]] << 2) | (unsigned)etype[e];  // < 40000
    combo[e] = (payload << 16) | (unsigned)rank;
}

// ---------------------------------------------------------------------------
// Kernel 3a: per-1024-block exclusive scan of deg (shfl-based, 2 barriers).
__global__ __launch_bounds__(SCAN_B)
void scan_block(const int* __restrict__ deg, int* __restrict__ off,
                int* __restrict__ bsum) {
    __shared__ int wsum[16];
    int i  = blockIdx.x * SCAN_B + threadIdx.x;
    int l  = threadIdx.x & 63;
    int wv = threadIdx.x >> 6;
    int v  = (i < N_NODES) ? deg[i] : 0;
    int s  = v;
#pragma unroll
    for (int d = 1; d < 64; d <<= 1) {
        int t = __shfl_up(s, d, 64);
        if (l >= d) s += t;
    }
    if (l == 63) wsum[wv] = s;            // wave totals
    __syncthreads();
    if (wv == 0) {
        int wval = (l < 16) ? wsum[l] : 0;
        int ss = wval;
#pragma unroll
        for (int d = 1; d < 16; d <<= 1) {
            int t = __shfl_up(ss, d, 64);
            if (l >= d) ss += t;
        }
        if (l == 15) bsum[blockIdx.x] = ss;      // block total
        if (l < 16)  wsum[l] = ss - wval;        // exclusive wave base
    }
    __syncthreads();
    if (i < N_NODES) off[i] = s - v + wsum[wv];  // block-local exclusive
}

// ---------------------------------------------------------------------------
// Kernel 3b: add global block base (each block wave-reduces its bsum prefix).
__global__ __launch_bounds__(SCAN_B)
void scan_add(int* __restrict__ off, const int* __restrict__ bsum) {
    __shared__ int base_sh;
    int blk = blockIdx.x;                 // 0..97
    if (threadIdx.x < 64) {
        int l = threadIdx.x;
        int a = (l < blk) ? bsum[l] : 0;
        int b = (l + 64 < blk) ? bsum[l + 64] : 0;
        int t = a + b;
#pragma unroll
        for (int d = 32; d > 0; d >>= 1) t += __shfl_xor(t, d, 64);
        if (l == 0) base_sh = t;
    }
    __syncthreads();
    int i = blk * SCAN_B + threadIdx.x;
    if (i < N_NODES) off[i] += base_sh;
    if (blk == 0 && threadIdx.x == 0) off[N_NODES] = N_EDGES;
}

// ---------------------------------------------------------------------------
// Kernel 4: atomic-free CSR scatter: pos = off[dst] + rank.
__global__ void scatter_pos(const int* __restrict__ dst,
                            const unsigned* __restrict__ combo,
                            const int* __restrict__ off,
                            unsigned short* __restrict__ elist) {
    int e = blockIdx.x * 256 + threadIdx.x;
    if (e >= N_EDGES) return;
    unsigned c = combo[e];
    int pos = off[dst[e]] + (int)(c & 0xFFFFu);
    elist[pos] = (unsigned short)(c >> 16);
}

// ---------------------------------------------------------------------------
// Kernel 5: per-dst aggregation, whole 64-edge chunk in flight.
// lane = (g<<4)|q : g = edge-slot group (4), q = feature quad (16).
__global__ void aggregate(const int* __restrict__ x,
                          const int* __restrict__ off,
                          const unsigned short* __restrict__ elist,
                          const float* __restrict__ T,
                          const float* __restrict__ bias,
                          float* __restrict__ node_out) {
    int tid = blockIdx.x * 256 + threadIdx.x;
    int w = tid >> 6;                  // dst node id
    if (w >= N_NODES) return;
    int l = tid & 63;
    int g = l >> 4;                    // edge-slot group
    int q = l & 15;                    // feature quad
    int beg = off[w], end = off[w + 1];

    // per-relation counts: one ballot per relation per 64-edge chunk
    int c0 = 0, c1 = 0, c2 = 0;
    for (int cb = beg; cb < end; cb += 64) {
        int idx = cb + l;
        unsigned pl = (idx < end) ? (unsigned)elist[idx] : 0xFFFFu;  // r=3 sentinel
        int r = (int)(pl & 3u);
        c0 += __popcll(__ballot(r == 0));
        c1 += __popcll(__ballot(r == 1));
        c2 += __popcll(__ballot(r == 2));
    }
    float inv0 = 1.f / fmaxf((float)c0, 1.f);
    float inv1 = 1.f / fmaxf((float)c1, 1.f);
    float inv2 = 1.f / fmaxf((float)c2, 1.f);

    float4 acc = {0.f, 0.f, 0.f, 0.f};
    for (int cb = beg; cb < end; cb += 64) {
        int idx = cb + l;
        unsigned pl = (idx < end) ? (unsigned)elist[idx] : 0xFFFFu;  // L1-hot reload
        int rem = end - cb; if (rem > 64) rem = 64;
#pragma unroll
        for (int k = 0; k < 16; ++k) {
            if (k * 4 >= rem) break;                     // wave-uniform exit
            unsigned p = __shfl(pl, k * 4 + g, 64);      // slot k*4+g payload
            bool valid = (p != 0xFFFFu);
            int r = valid ? (int)(p & 3u) : 0;
            int v = valid ? (int)(p >> 2) : 0;
            float iv = (r == 0) ? inv0 : ((r == 1) ? inv1 : inv2);
            iv = valid ? iv : 0.f;
            const float4 t = *(const float4*)(T + ((size_t)(1 + r) * VOCAB + v) * DIM + q * 4);
            acc.x += t.x * iv; acc.y += t.y * iv;
            acc.z += t.z * iv; acc.w += t.w * iv;
        }
    }
    // combine the 4 edge-slot groups
    acc.x += __shfl_xor(acc.x, 16, 64); acc.x += __shfl_xor(acc.x, 32, 64);
    acc.y += __shfl_xor(acc.y, 16, 64); acc.y += __shfl_xor(acc.y, 32, 64);
    acc.z += __shfl_xor(acc.z, 16, 64); acc.z += __shfl_xor(acc.z, 32, 64);
    acc.w += __shfl_xor(acc.w, 16, 64); acc.w += __shfl_xor(acc.w, 32, 64);

    if (g == 0) {                      // lanes 0..15 write the 64-float row
        int v0 = x[w];
        const float4 rt = *(const float4*)(T + (size_t)v0 * DIM + q * 4);
        const float4 b4 = *(const float4*)(bias + q * 4);
        float4 o;
        o.x = fmaxf(rt.x + b4.x + acc.x, 0.f);
        o.y = fmaxf(rt.y + b4.y + acc.y, 0.f);
        o.z = fmaxf(rt.z + b4.z + acc.z, 0.f);
        o.w = fmaxf(rt.w + b4.w + acc.w, 0.f);
        *(float4*)(node_out + (size_t)w * DIM + q * 4) = o;
    }
}

// ---------------------------------------------------------------------------
// Kernel 6: per-graph mean pool + 64->2 linear. batch is SORTED. 8 waves/blk.
__device__ __forceinline__ int lbound(const int* __restrict__ b, int val) {
    int lo = 0, hi = N_NODES;
    while (lo < hi) {
        int mid = (lo + hi) >> 1;
        if (b[mid] < val) lo = mid + 1; else hi = mid;
    }
    return lo;
}

__global__ __launch_bounds__(512)
void pool_linear(const int* __restrict__ batch,
                 const float* __restrict__ node_out,
                 const float* __restrict__ lin_W,
                 const float* __restrict__ lin_b,
                 float* __restrict__ out) {
    __shared__ float sh[512];
    int g = blockIdx.x;
    int lane = threadIdx.x & 63;
    int w = threadIdx.x >> 6;      // 0..7
    int s = lbound(batch, g);
    int e = lbound(batch, g + 1);
    float acc = 0.f;
    for (int i = s + w; i < e; i += 8)
        acc += node_out[(size_t)i * DIM + lane];
    sh[threadIdx.x] = acc;
    __syncthreads();
    if (w == 0) {
        float tot = 0.f;
#pragma unroll
        for (int k = 0; k < 8; ++k) tot += sh[k * 64 + lane];
        float cnt = (float)(e - s);
        float mean = (e > s) ? tot / cnt : 0.f;
        float p0 = mean * lin_W[lane * 2 + 0];
        float p1 = mean * lin_W[lane * 2 + 1];
#pragma unroll
        for (int off2 = 32; off2 > 0; off2 >>= 1) {
            p0 += __shfl_down(p0, off2, 64);
            p1 += __shfl_down(p1, off2, 64);
        }
        if (lane == 0) {
            out[g * 2 + 0] = p0 + lin_b[0];
            out[g * 2 + 1] = p1 + lin_b[1];
        }
    }
}

// ---------------------------------------------------------------------------
extern "C" void kernel_launch(void* const* d_in, const int* in_sizes, int n_in,
                              void* d_out, int out_size, void* d_ws, size_t ws_size,
                              hipStream_t stream) {
    const int*   x      = (const int*)d_in[0];
    const int*   eidx   = (const int*)d_in[1];   // [2, E]
    const int*   etype  = (const int*)d_in[2];
    const int*   batch  = (const int*)d_in[3];
    const float* embed  = (const float*)d_in[4];
    const float* W_rel  = (const float*)d_in[5];
    const float* W_root = (const float*)d_in[6];
    const float* bias   = (const float*)d_in[7];
    const float* lin_W  = (const float*)d_in[8];
    const float* lin_b  = (const float*)d_in[9];
    float* out = (float*)d_out;

    const int* src = eidx;
    const int* dst = eidx + N_EDGES;

    // Workspace layout (bytes):
    //   elist    : 1M * 2        = 2,000,000  (first 400,000 aliased as deg:
    //                                          deg dead after scan_block)
    //   off      : (N+1)*4       =   400,016
    //   bsum     : 98*4
    //   T        : 4*VOCAB*64*4  = 10,240,000  (at +2,802,176)
    //   node_out : N*64*4        = 25,600,000  (first 4,000,000 aliased as
    //                              combo: combo dead before aggregate)
    char* ws = (char*)d_ws;
    unsigned short* elist = (unsigned short*)(ws);
    int* deg    = (int*)(ws);                    // alias: dead before elist written
    int* off    = (int*)(ws + 2000000);
    int* bsum   = (int*)(ws + 2400016);
    float* T        = (float*)(ws + 2802176);
    float* node_out = (float*)(ws + 13042176);
    unsigned* combo = (unsigned*)(ws + 13042176); // alias: dead before node_out written

    // Zero only the degree histogram.
    hipMemsetAsync(deg, 0, N_NODES * sizeof(int), stream);

    // 1. fused histogram + rank + payload (the ONLY atomic pass)
    edge_prep<<<(N_EDGES + 255) / 256, 256, 0, stream>>>(src, dst, etype, x, deg, combo);

    // 2. exclusive scan deg -> off
    scan_block<<<N_SCAN_BLOCKS, SCAN_B, 0, stream>>>(deg, off, bsum);
    scan_add<<<N_SCAN_BLOCKS, SCAN_B, 0, stream>>>(off, bsum);

    // 3. atomic-free CSR scatter (overwrites deg alias region — deg is dead)
    scatter_pos<<<(N_EDGES + 255) / 256, 256, 0, stream>>>(dst, combo, off, elist);

    // 4. transformed tables (needed only by aggregate)
    build_tables<<<(4 * VOCAB) / 16, 256, 0, stream>>>(embed, W_rel, W_root, T);

    // 5. per-node aggregation (no atomics, full chunk of loads in flight)
    aggregate<<<(N_NODES * 64) / 256, 256, 0, stream>>>(x, off, elist, T, bias, node_out);

    // 6. per-graph pool + linear (no atomics)
    pool_linear<<<N_GRAPHS, 512, 0, stream>>>(batch, node_out, lin_W, lin_b, out);
}

// Round 6
// 151.644 us; speedup vs baseline: 1.3992x; 1.0175x over previous
//
#include <hip/hip_runtime.h>

#define N_NODES 100000
#define N_EDGES 1000000
#define N_GRAPHS 512
#define VOCAB 10000
#define DIM 64

#define SCAN_B 1024
#define N_SCAN_BLOCKS ((N_NODES + SCAN_B - 1) / SCAN_B)   // 98
#define PREP_BLOCKS ((N_EDGES + 255) / 256)               // 3907
#define BUILD_BLOCKS ((4 * VOCAB) / 16)                   // 2500

typedef unsigned short ushort_t;

// f32 -> bf16 round-to-nearest-even (bit trick; inputs finite)
static __device__ __forceinline__ ushort_t f2bf(float f) {
    unsigned u = __float_as_uint(f);
    unsigned r = 0x7FFFu + ((u >> 16) & 1u);
    return (ushort_t)((u + r) >> 16);
}
// bf16 bits (low half of u32 pair) -> f32
#define BFLO(u) __uint_as_float((u) << 16)
#define BFHI(u) __uint_as_float((u) & 0xFFFF0000u)

// ---------------------------------------------------------------------------
// Kernel A (fused): blocks [0, PREP_BLOCKS) do edge_prep; the rest build the
// bf16 transformed tables Tb[m][v][j] = (embed @ W_m) in bf16.
__global__ void prep_and_build(const int* __restrict__ src,
                               const int* __restrict__ dst,
                               const int* __restrict__ etype,
                               const int* __restrict__ x,
                               int* __restrict__ deg,
                               unsigned* __restrict__ combo,
                               const float* __restrict__ embed,
                               const float* __restrict__ W_rel,
                               const float* __restrict__ W_root,
                               ushort_t* __restrict__ Tb) {
    if (blockIdx.x < PREP_BLOCKS) {
        // --- edge_prep: histogram atomic returns within-dst rank ---
        int e = blockIdx.x * 256 + threadIdx.x;
        if (e >= N_EDGES) return;
        int rank = atomicAdd(&deg[dst[e]], 1);            // deg ~ Poisson(10) << 2^16
        unsigned payload = ((unsigned)x[src[e]] << 2) | (unsigned)etype[e];
        combo[e] = (payload << 16) | (unsigned)rank;
    } else {
        // --- build_tables: 4 rows per wave; float4 math, bf16 store ---
        int tid  = (blockIdx.x - PREP_BLOCKS) * 256 + threadIdx.x;
        int l    = tid & 63;
        int wave = tid >> 6;              // 0..9999
        int sub  = l >> 4;                // row-within-wave 0..3
        int q    = l & 15;                // feature quad
        int row  = wave * 4 + sub;        // wave never crosses m (10000%4==0)
        int m    = row / VOCAB;
        int v    = row - m * VOCAB;
        const float* W = (m == 0) ? W_root : (W_rel + (size_t)(m - 1) * DIM * DIM);
        float4 e4  = *(const float4*)(embed + (size_t)v * DIM + q * 4);
        float4 acc = {0.f, 0.f, 0.f, 0.f};
#pragma unroll
        for (int kk = 0; kk < 16; ++kk) {
            int srcl = sub * 16 + kk;
            float ex = __shfl(e4.x, srcl, 64);
            float ey = __shfl(e4.y, srcl, 64);
            float ez = __shfl(e4.z, srcl, 64);
            float ew = __shfl(e4.w, srcl, 64);
            const float4 w0 = *(const float4*)(W + (4 * kk + 0) * DIM + q * 4);
            const float4 w1 = *(const float4*)(W + (4 * kk + 1) * DIM + q * 4);
            const float4 w2 = *(const float4*)(W + (4 * kk + 2) * DIM + q * 4);
            const float4 w3 = *(const float4*)(W + (4 * kk + 3) * DIM + q * 4);
            acc.x += ex * w0.x; acc.y += ex * w0.y; acc.z += ex * w0.z; acc.w += ex * w0.w;
            acc.x += ey * w1.x; acc.y += ey * w1.y; acc.z += ey * w1.z; acc.w += ey * w1.w;
            acc.x += ez * w2.x; acc.y += ez * w2.y; acc.z += ez * w2.z; acc.w += ez * w2.w;
            acc.x += ew * w3.x; acc.y += ew * w3.y; acc.z += ew * w3.z; acc.w += ew * w3.w;
        }
        ushort_t* p = Tb + (size_t)row * DIM + q * 4;     // 8B-aligned
        p[0] = f2bf(acc.x); p[1] = f2bf(acc.y);
        p[2] = f2bf(acc.z); p[3] = f2bf(acc.w);
    }
}

// ---------------------------------------------------------------------------
// Kernel B1: per-1024-block exclusive scan of deg (shfl-based, 2 barriers).
__global__ __launch_bounds__(SCAN_B)
void scan_block(const int* __restrict__ deg, int* __restrict__ off,
                int* __restrict__ bsum) {
    __shared__ int wsum[16];
    int i  = blockIdx.x * SCAN_B + threadIdx.x;
    int l  = threadIdx.x & 63;
    int wv = threadIdx.x >> 6;
    int v  = (i < N_NODES) ? deg[i] : 0;
    int s  = v;
#pragma unroll
    for (int d = 1; d < 64; d <<= 1) {
        int t = __shfl_up(s, d, 64);
        if (l >= d) s += t;
    }
    if (l == 63) wsum[wv] = s;
    __syncthreads();
    if (wv == 0) {
        int wval = (l < 16) ? wsum[l] : 0;
        int ss = wval;
#pragma unroll
        for (int d = 1; d < 16; d <<= 1) {
            int t = __shfl_up(ss, d, 64);
            if (l >= d) ss += t;
        }
        if (l == 15) bsum[blockIdx.x] = ss;
        if (l < 16)  wsum[l] = ss - wval;
    }
    __syncthreads();
    if (i < N_NODES) off[i] = s - v + wsum[wv];
}

// Kernel B2: add global block base.
__global__ __launch_bounds__(SCAN_B)
void scan_add(int* __restrict__ off, const int* __restrict__ bsum) {
    __shared__ int base_sh;
    int blk = blockIdx.x;
    if (threadIdx.x < 64) {
        int l = threadIdx.x;
        int a = (l < blk) ? bsum[l] : 0;
        int b = (l + 64 < blk) ? bsum[l + 64] : 0;
        int t = a + b;
#pragma unroll
        for (int d = 32; d > 0; d >>= 1) t += __shfl_xor(t, d, 64);
        if (l == 0) base_sh = t;
    }
    __syncthreads();
    int i = blk * SCAN_B + threadIdx.x;
    if (i < N_NODES) off[i] += base_sh;
    if (blk == 0 && threadIdx.x == 0) off[N_NODES] = N_EDGES;
}

// ---------------------------------------------------------------------------
// Kernel C: atomic-free CSR scatter: pos = off[dst] + rank.
__global__ void scatter_pos(const int* __restrict__ dst,
                            const unsigned* __restrict__ combo,
                            const int* __restrict__ off,
                            ushort_t* __restrict__ elist) {
    int e = blockIdx.x * 256 + threadIdx.x;
    if (e >= N_EDGES) return;
    unsigned c = combo[e];
    int pos = off[dst[e]] + (int)(c & 0xFFFFu);
    elist[pos] = (ushort_t)(c >> 16);
}

// ---------------------------------------------------------------------------
// Kernel D: per-dst aggregation from bf16 tables.
// lane = (g<<3)|q : g = edge-slot group (8 slots/iter), q = feature octet.
// Each lane loads one dwordx4 (8 bf16 = 16B) of a T row per slot.
__global__ void aggregate(const int* __restrict__ x,
                          const int* __restrict__ off,
                          const ushort_t* __restrict__ elist,
                          const ushort_t* __restrict__ Tb,
                          const float* __restrict__ bias,
                          float* __restrict__ node_out) {
    int tid = blockIdx.x * 256 + threadIdx.x;
    int w = tid >> 6;                  // dst node id
    if (w >= N_NODES) return;
    int l = tid & 63;
    int g = l >> 3;                    // edge-slot group 0..7
    int q = l & 7;                     // feature octet 0..7
    int beg = off[w], end = off[w + 1];

    // per-relation counts: ballots over each 64-edge chunk
    int c0 = 0, c1 = 0, c2 = 0;
    for (int cb = beg; cb < end; cb += 64) {
        int idx = cb + l;
        unsigned pl = (idx < end) ? (unsigned)elist[idx] : 0xFFFFu;  // r=3 sentinel
        int r = (int)(pl & 3u);
        c0 += __popcll(__ballot(r == 0));
        c1 += __popcll(__ballot(r == 1));
        c2 += __popcll(__ballot(r == 2));
    }
    float inv0 = 1.f / fmaxf((float)c0, 1.f);
    float inv1 = 1.f / fmaxf((float)c1, 1.f);
    float inv2 = 1.f / fmaxf((float)c2, 1.f);

    float a0 = 0.f, a1 = 0.f, a2 = 0.f, a3 = 0.f,
          a4 = 0.f, a5 = 0.f, a6 = 0.f, a7 = 0.f;
    for (int cb = beg; cb < end; cb += 64) {
        int idx = cb + l;
        unsigned pl = (idx < end) ? (unsigned)elist[idx] : 0xFFFFu;  // L1-hot reload
        int rem = end - cb; if (rem > 64) rem = 64;
#pragma unroll
        for (int k = 0; k < 8; ++k) {
            if (k * 8 >= rem) break;                     // wave-uniform exit
            unsigned p = (unsigned)__shfl((int)pl, k * 8 + g, 64);
            bool valid = (p != 0xFFFFu);
            int r = valid ? (int)(p & 3u) : 0;
            int v = valid ? (int)(p >> 2) : 0;
            float iv = (r == 0) ? inv0 : ((r == 1) ? inv1 : inv2);
            iv = valid ? iv : 0.f;
            const uint4 t = *(const uint4*)(Tb + ((size_t)(1 + r) * VOCAB + v) * DIM + q * 8);
            a0 += BFLO(t.x) * iv; a1 += BFHI(t.x) * iv;
            a2 += BFLO(t.y) * iv; a3 += BFHI(t.y) * iv;
            a4 += BFLO(t.z) * iv; a5 += BFHI(t.z) * iv;
            a6 += BFLO(t.w) * iv; a7 += BFHI(t.w) * iv;
        }
    }
    // combine the 8 edge-slot groups (lanes with same q)
    a0 += __shfl_xor(a0, 8, 64); a0 += __shfl_xor(a0, 16, 64); a0 += __shfl_xor(a0, 32, 64);
    a1 += __shfl_xor(a1, 8, 64); a1 += __shfl_xor(a1, 16, 64); a1 += __shfl_xor(a1, 32, 64);
    a2 += __shfl_xor(a2, 8, 64); a2 += __shfl_xor(a2, 16, 64); a2 += __shfl_xor(a2, 32, 64);
    a3 += __shfl_xor(a3, 8, 64); a3 += __shfl_xor(a3, 16, 64); a3 += __shfl_xor(a3, 32, 64);
    a4 += __shfl_xor(a4, 8, 64); a4 += __shfl_xor(a4, 16, 64); a4 += __shfl_xor(a4, 32, 64);
    a5 += __shfl_xor(a5, 8, 64); a5 += __shfl_xor(a5, 16, 64); a5 += __shfl_xor(a5, 32, 64);
    a6 += __shfl_xor(a6, 8, 64); a6 += __shfl_xor(a6, 16, 64); a6 += __shfl_xor(a6, 32, 64);
    a7 += __shfl_xor(a7, 8, 64); a7 += __shfl_xor(a7, 16, 64); a7 += __shfl_xor(a7, 32, 64);

    if (g == 0) {                      // lanes 0..7 write the 64-float row
        const uint4 rt = *(const uint4*)(Tb + (size_t)x[w] * DIM + q * 8);
        const float4 b0 = *(const float4*)(bias + q * 8);
        const float4 b1 = *(const float4*)(bias + q * 8 + 4);
        float4 o0, o1;
        o0.x = fmaxf(BFLO(rt.x) + b0.x + a0, 0.f);
        o0.y = fmaxf(BFHI(rt.x) + b0.y + a1, 0.f);
        o0.z = fmaxf(BFLO(rt.y) + b0.z + a2, 0.f);
        o0.w = fmaxf(BFHI(rt.y) + b0.w + a3, 0.f);
        o1.x = fmaxf(BFLO(rt.z) + b1.x + a4, 0.f);
        o1.y = fmaxf(BFHI(rt.z) + b1.y + a5, 0.f);
        o1.z = fmaxf(BFLO(rt.w) + b1.z + a6, 0.f);
        o1.w = fmaxf(BFHI(rt.w) + b1.w + a7, 0.f);
        float* dstp = node_out + (size_t)w * DIM + q * 8;
        *(float4*)(dstp)     = o0;
        *(float4*)(dstp + 4) = o1;
    }
}

// ---------------------------------------------------------------------------
// Kernel E: per-graph mean pool + 64->2 linear. batch is SORTED. 8 waves/blk.
__device__ __forceinline__ int lbound(const int* __restrict__ b, int val) {
    int lo = 0, hi = N_NODES;
    while (lo < hi) {
        int mid = (lo + hi) >> 1;
        if (b[mid] < val) lo = mid + 1; else hi = mid;
    }
    return lo;
}

__global__ __launch_bounds__(512)
void pool_linear(const int* __restrict__ batch,
                 const float* __restrict__ node_out,
                 const float* __restrict__ lin_W,
                 const float* __restrict__ lin_b,
                 float* __restrict__ out) {
    __shared__ float sh[512];
    int g = blockIdx.x;
    int lane = threadIdx.x & 63;
    int w = threadIdx.x >> 6;      // 0..7
    int s = lbound(batch, g);
    int e = lbound(batch, g + 1);
    float acc = 0.f;
    for (int i = s + w; i < e; i += 8)
        acc += node_out[(size_t)i * DIM + lane];
    sh[threadIdx.x] = acc;
    __syncthreads();
    if (w == 0) {
        float tot = 0.f;
#pragma unroll
        for (int k = 0; k < 8; ++k) tot += sh[k * 64 + lane];
        float cnt = (float)(e - s);
        float mean = (e > s) ? tot / cnt : 0.f;
        float p0 = mean * lin_W[lane * 2 + 0];
        float p1 = mean * lin_W[lane * 2 + 1];
#pragma unroll
        for (int off2 = 32; off2 > 0; off2 >>= 1) {
            p0 += __shfl_down(p0, off2, 64);
            p1 += __shfl_down(p1, off2, 64);
        }
        if (lane == 0) {
            out[g * 2 + 0] = p0 + lin_b[0];
            out[g * 2 + 1] = p1 + lin_b[1];
        }
    }
}

// ---------------------------------------------------------------------------
extern "C" void kernel_launch(void* const* d_in, const int* in_sizes, int n_in,
                              void* d_out, int out_size, void* d_ws, size_t ws_size,
                              hipStream_t stream) {
    const int*   x      = (const int*)d_in[0];
    const int*   eidx   = (const int*)d_in[1];   // [2, E]
    const int*   etype  = (const int*)d_in[2];
    const int*   batch  = (const int*)d_in[3];
    const float* embed  = (const float*)d_in[4];
    const float* W_rel  = (const float*)d_in[5];
    const float* W_root = (const float*)d_in[6];
    const float* bias   = (const float*)d_in[7];
    const float* lin_W  = (const float*)d_in[8];
    const float* lin_b  = (const float*)d_in[9];
    float* out = (float*)d_out;

    const int* src = eidx;
    const int* dst = eidx + N_EDGES;

    // Workspace layout (bytes):
    //   elist    : 1M*2          = 2,000,000  (first 400,000 aliased as deg:
    //                                          deg dead after scan_block)
    //   off      : (N+1)*4       =   400,016
    //   bsum     : 98*4          (pad to keep Tb 16B-aligned)
    //   Tb       : 4*VOCAB*64*2  = 5,120,000   bf16 tables (at +2,802,176)
    //   node_out : N*64*4        = 25,600,000  (first 4,000,000 aliased as
    //                              combo: combo dead before aggregate)
    char* ws = (char*)d_ws;
    ushort_t* elist = (ushort_t*)(ws);
    int* deg    = (int*)(ws);                    // alias: dead before elist written
    int* off    = (int*)(ws + 2000000);
    int* bsum   = (int*)(ws + 2400016);
    ushort_t* Tb    = (ushort_t*)(ws + 2802176);
    float* node_out = (float*)(ws + 7922176);
    unsigned* combo = (unsigned*)(ws + 7922176); // alias: dead before node_out written

    // Zero only the degree histogram.
    hipMemsetAsync(deg, 0, N_NODES * sizeof(int), stream);

    // 1. fused: histogram+rank+payload (atomic pass)  ||  bf16 table build
    prep_and_build<<<PREP_BLOCKS + BUILD_BLOCKS, 256, 0, stream>>>(
        src, dst, etype, x, deg, combo, embed, W_rel, W_root, Tb);

    // 2. exclusive scan deg -> off
    scan_block<<<N_SCAN_BLOCKS, SCAN_B, 0, stream>>>(deg, off, bsum);
    scan_add<<<N_SCAN_BLOCKS, SCAN_B, 0, stream>>>(off, bsum);

    // 3. atomic-free CSR scatter (overwrites deg alias region — deg is dead)
    scatter_pos<<<(N_EDGES + 255) / 256, 256, 0, stream>>>(dst, combo, off, elist);

    // 4. per-node aggregation from bf16 tables
    aggregate<<<(N_NODES * 64) / 256, 256, 0, stream>>>(x, off, elist, Tb, bias, node_out);

    // 5. per-graph pool + linear
    pool_linear<<<N_GRAPHS, 512, 0, stream>>>(batch, node_out, lin_W, lin_b, out);
}